// Round 14
// baseline (548.148 us; speedup 1.0000x reference)
//
#include <hip/hip_runtime.h>
#include <math.h>

typedef unsigned int u32;
typedef __attribute__((ext_vector_type(2))) _Float16 h2;
typedef __attribute__((ext_vector_type(8))) _Float16 h8;
typedef __attribute__((ext_vector_type(4))) float f32x4;

#define MFMA16H(a,b,c) __builtin_amdgcn_mfma_f32_16x16x32_f16(a,b,c,0,0,0)

// ---------- f16 packed helpers ----------
__device__ __forceinline__ u32 pkrtz(float a, float b){
  auto r = __builtin_amdgcn_cvt_pkrtz(a, b);   // __fp16 ext_vector(2)
  return *(u32*)&r;
}
__device__ __forceinline__ uint4 pack8h(const float* f){
  uint4 v; v.x = pkrtz(f[0],f[1]); v.y = pkrtz(f[2],f[3]);
  v.z = pkrtz(f[4],f[5]); v.w = pkrtz(f[6],f[7]); return v;
}
__device__ __forceinline__ u32 pk_add(u32 a, u32 b){
  h2 r = *(h2*)&a + *(h2*)&b; return *(u32*)&r;
}
__device__ __forceinline__ u32 pk_mul(u32 a, u32 b){
  h2 r = *(h2*)&a * *(h2*)&b; return *(u32*)&r;
}
__device__ __forceinline__ u32 pk_relu(u32 a){
  h2 z = {(_Float16)0.f, (_Float16)0.f};
  h2 r = __builtin_elementwise_max(*(h2*)&a, z);
  return *(u32*)&r;
}

// async global->LDS, 16B/lane; dest = wave-uniform base + lane*16 (src per-lane OK)
__device__ __forceinline__ void gload_lds16(const void* g, void* l){
  __builtin_amdgcn_global_load_lds((const __attribute__((address_space(1))) unsigned int*)g,
                                   (__attribute__((address_space(3))) unsigned int*)l,
                                   16, 0, 0);
}

// LDS fragment offset (shorts) in paired-macro-row granule layout
__device__ __forceinline__ int frag_off(int f, int quad){
  return (f>>1)*64 + (f&1)*32 + ((quad ^ ((f>>1)&3))*8);
}

// f16-row granule swizzle: row = 32 granules x 8 halfs; mixes ch (=g>>1) and row into banks
__device__ __forceinline__ int xg2(int g, int r){ return g ^ ((r ^ (g>>1)) & 7); }

// ---------- merged init kernel: weight-convert + per-edge pre + small zeroing ----------
__global__ void k_init(const float* __restrict__ inW2, const float* __restrict__ gW1,
                       const float* __restrict__ gW2, const float* __restrict__ oW1,
                       const float* __restrict__ oW2,
                       short* __restrict__ w2t, short* __restrict__ gw1t,
                       short* __restrict__ gw2t, short* __restrict__ ow1t,
                       short* __restrict__ ow2t,
                       const int* __restrict__ ei, const int* __restrict__ n2g,
                       const int* __restrict__ nl, const float* __restrict__ sigmas,
                       const float* __restrict__ pos, const float* __restrict__ dn, int E,
                       float* __restrict__ pd, int* __restrict__ cnt, int* __restrict__ inlist,
                       float* __restrict__ out, int G, short* __restrict__ attrPad){
  int blk = blockIdx.x;
  int tid = threadIdx.x;
  if (blk < 368){
    int gidx = blk*256 + tid;
    const float* src; short* dst; int t, K8, Nf;
    if (gidx < 8192)      { src = inW2; dst = w2t; t = gidx; K8 = 32; Nf = 256; }
    else if (gidx < 40960){ int r = gidx-8192;  int c = r>>13; t = r&8191;
                            src = gW1 + (size_t)c*65536; dst = gw1t + (size_t)c*65536; K8 = 32; Nf = 256; }
    else if (gidx < 73728){ int r = gidx-40960; int c = r>>13; t = r&8191;
                            src = gW2 + (size_t)c*65536; dst = gw2t + (size_t)c*65536; K8 = 32; Nf = 256; }
    else if (gidx < 90112){ t = gidx-73728; src = oW1; dst = ow1t; K8 = 64; Nf = 256; }
    else if (gidx < 94208){ t = gidx-90112; src = oW2; dst = ow2t; K8 = 32; Nf = 128; }
    else return;
    int f = t / K8, c = t - f*K8;
    float v[8];
    #pragma unroll
    for (int j=0;j<8;j++) v[j] = src[(size_t)(c*8+j)*Nf + f];
    ((uint4*)dst)[t] = pack8h(v);
  } else if (blk < 1088){
    int e = (blk-368)*256 + tid;
    if (e >= E) return;
    int r = ei[e], c = ei[E+e];
    float sg = sigmas[nl[n2g[r]]];
    float dx = pos[3*r]-pos[3*c], dy = pos[3*r+1]-pos[3*c+1], dz = pos[3*r+2]-pos[3*c+2];
    float d = sqrtf(dx*dx + dy*dy + dz*dz);
    pd[e] = d + dn[e]*sg;
    int slot = atomicAdd(&cnt[c], 1);
    if (slot < 8) inlist[c*8 + slot] = e;
  } else if (blk == 1088){
    for (int i = tid; i < G; i += 256) out[i] = 0.f;
  } else {
    if (tid < 128) ((u32*)attrPad)[tid] = 0u;
  }
}

// ---------- edge_attr: barrier-free, no LDS. B computed in registers ----------
__global__ __launch_bounds__(256) void k_attr(
    const float* __restrict__ pd, const float* __restrict__ W1, const float* __restrict__ b1,
    const short* __restrict__ W2t, const float* __restrict__ b2,
    const int* __restrict__ etype, const float* __restrict__ eemb,
    short* __restrict__ attr, int E)
{
  int tid = threadIdx.x;
  int base = blockIdx.x*64;
  int wv = tid>>6, lane = tid&63, quad = lane>>4, l15 = lane&15;
  float pdv[4];
  #pragma unroll
  for (int nt=0;nt<4;nt++) pdv[nt] = pd[base + nt*16 + l15];
  f32x4 acc[4][4];
  #pragma unroll
  for (int mt=0;mt<4;mt++) for (int nt=0;nt<4;nt++) acc[mt][nt] = (f32x4)0.f;
  #pragma unroll
  for (int s=0; s<8; s++){
    int k0 = s*32 + quad*8;
    float4 w1a = *(const float4*)(W1 + k0), w1b = *(const float4*)(W1 + k0 + 4);
    float4 b1a = *(const float4*)(b1 + k0), b1b = *(const float4*)(b1 + k0 + 4);
    h8 a[4], b[4];
    #pragma unroll
    for (int mt=0;mt<4;mt++){
      int f = (wv*4+mt)*16 + l15;
      a[mt] = *(const h8*)(W2t + (size_t)f*256 + k0);
    }
    #pragma unroll
    for (int nt=0;nt<4;nt++){
      float p = pdv[nt];
      float f[8] = {fmaxf(p*w1a.x+b1a.x,0.f), fmaxf(p*w1a.y+b1a.y,0.f),
                    fmaxf(p*w1a.z+b1a.z,0.f), fmaxf(p*w1a.w+b1a.w,0.f),
                    fmaxf(p*w1b.x+b1b.x,0.f), fmaxf(p*w1b.y+b1b.y,0.f),
                    fmaxf(p*w1b.z+b1b.z,0.f), fmaxf(p*w1b.w+b1b.w,0.f)};
      uint4 u = pack8h(f);
      b[nt] = *(h8*)&u;
    }
    #pragma unroll
    for (int mt=0;mt<4;mt++)
      #pragma unroll
      for (int nt=0;nt<4;nt++)
        acc[mt][nt] = MFMA16H(a[mt], b[nt], acc[mt][nt]);
  }
  #pragma unroll
  for (int nt=0;nt<4;nt++){
    int e = base + nt*16 + l15;
    int et = etype[e];
    #pragma unroll
    for (int mt=0;mt<4;mt++){
      int f0 = (wv*4+mt)*16 + quad*4;
      float4 bb = *(const float4*)(b2 + f0);
      float4 em = *(const float4*)(eemb + (size_t)et*256 + f0);
      float v0 = (acc[mt][nt][0]+bb.x)*em.x, v1 = (acc[mt][nt][1]+bb.y)*em.y;
      float v2 = (acc[mt][nt][2]+bb.z)*em.z, v3 = (acc[mt][nt][3]+bb.w)*em.w;
      uint2 v; v.x = pkrtz(v0,v1); v.y = pkrtz(v2,v3);
      *(uint2*)(attr + (size_t)e*256 + f0) = v;
    }
  }
}

// ---------- fused 4-conv kernel: 2 GRAPHS (64 nodes) per block, 512 threads ----------
// Round-14: gather restructured FOUR sequential 8-feat passes, each with a
// hand-staged 8-deep attr load batch (av[8]/xv[8] arrays). r13 diagnosis:
// kernel at per-CU HBM-stream rate, MLP-limited (~2 loads in flight/wave).
// Per-pass live set: 16 uint4 + acc + topo + addr ~= 95 < 128-reg cap of
// (512,4) -> no spill; in-flight global bytes/wave x4.
__global__ __launch_bounds__(512,4) void k_conv4(
    const int* __restrict__ at, const float* __restrict__ nemb,
    const short* __restrict__ attrS, const int* __restrict__ ei,
    const int* __restrict__ cnt, const int* __restrict__ inlist,
    const short* __restrict__ gw1t, const float* __restrict__ gb1,
    const short* __restrict__ gw2t, const float* __restrict__ gb2,
    short* __restrict__ xF, int E, int N)
{
  __shared__ short xls[65*256];       // 32.5 KB f16 state (64 nodes); row 64 = zero
  __shared__ uint4 AlsV[64*32];       // 32 KB; Als aliases T1
  short* Als = (short*)AlsV;
  short* T1  = (short*)AlsV;
  int tid = threadIdx.x;
  int nbase = blockIdx.x*64;
  int wv = tid>>6, lane = tid&63, quad = lane>>4, l15 = lane&15;
  int jl = tid>>3, ch4 = tid&7;       // 8 threads/node, 32 feats each

  // ---- topology: unconditional loads + selects, packed e|r<<20 (r<=64: 7b) ----
  int topo[8];
  {
    int j = nbase + jl;
    int jj = (j < N) ? j : 0;
    int deg = (j < N) ? min(cnt[jj], 8) : 0;
    int4 L0 = *(const int4*)(inlist + jj*8);
    int4 L1 = *(const int4*)(inlist + jj*8 + 4);
    int raw[8] = {L0.x,L0.y,L0.z,L0.w,L1.x,L1.y,L1.z,L1.w};
    #pragma unroll
    for (int s=0;s<8;s++){
      int e = (s < deg) ? raw[s] : E;            // E = zeroed attr row
      int r = ei[e] - nbase;                     // ei[E] in-bounds (2E array)
      if (s >= deg) r = 64;                      // 64 = zeroed x row
      topo[s] = e | (r << 20);
    }
  }
  // ---- init xls (f16) from node_emb[at]; zero row 64 ----
  {
    int j = nbase + jl;
    int a = (j < N) ? at[j] : 0;
    const float* src = nemb + (size_t)a*256 + ch4*32;
    #pragma unroll
    for (int q=0;q<4;q++){
      float f[8];
      float4 v0 = *(const float4*)(src + q*8);
      float4 v1 = *(const float4*)(src + q*8 + 4);
      f[0]=v0.x; f[1]=v0.y; f[2]=v0.z; f[3]=v0.w;
      f[4]=v1.x; f[5]=v1.y; f[6]=v1.z; f[7]=v1.w;
      *(uint4*)(xls + jl*256 + xg2(ch4*4+q, jl)*8) = pack8h(f);
    }
    if (tid < 32){ uint4 z; z.x=z.y=z.z=z.w=0u; ((uint4*)(xls + 64*256))[tid] = z; }
  }
  __syncthreads();
  for (int c=0; c<4; c++){
    const short* W1t = gw1t + (size_t)c*65536;
    const short* W2t = gw2t + (size_t)c*65536;
    const float* b1 = gb1 + c*256;
    const float* b2 = gb2 + c*256;
    // ---- gather into Als: FOUR sequential 8-feat passes; 8-deep load batch ----
    // hin[j] = x[j] + sum relu(x[r]+attr[e]); pads hit zero rows -> relu(0)=0
    #pragma unroll 1
    for (int q=0; q<4; q++){
      int c0 = ch4*4 + q;
      uint4 A = *(const uint4*)(xls + jl*256 + xg2(c0, jl)*8);
      uint4 av[8], xv[8];
      #pragma unroll
      for (int s=0; s<8; s++){
        int e = topo[s] & 0xFFFFF;
        int r = topo[s] >> 20;
        av[s] = *(const uint4*)(attrS + (size_t)e*256 + ch4*32 + q*8);
        xv[s] = *(const uint4*)(xls + r*256 + xg2(c0, r)*8);
      }
      #pragma unroll
      for (int s=0; s<8; s++){
        A.x = pk_add(A.x, pk_relu(pk_add(xv[s].x, av[s].x)));
        A.y = pk_add(A.y, pk_relu(pk_add(xv[s].y, av[s].y)));
        A.z = pk_add(A.z, pk_relu(pk_add(xv[s].z, av[s].z)));
        A.w = pk_add(A.w, pk_relu(pk_add(xv[s].w, av[s].w)));
      }
      *(uint4*)(Als + jl*256 + ((c0 ^ (jl&7))*8)) = A;
    }
    __syncthreads();
    // ---- GEMM1: M=256 (8 waves x 32 feats), N=64, K=256; A direct from L2 ----
    f32x4 acc[2][4];
    #pragma unroll
    for (int mt=0;mt<2;mt++) for (int nt=0;nt<4;nt++) acc[mt][nt] = (f32x4)0.f;
    #pragma unroll
    for (int s=0; s<8; s++){
      h8 a[2], b[4];
      #pragma unroll
      for (int mt=0;mt<2;mt++)
        a[mt] = *(const h8*)(W1t + (size_t)((wv*2+mt)*16 + l15)*256 + s*32 + quad*8);
      #pragma unroll
      for (int nt=0;nt<4;nt++){
        int n = nt*16 + l15; int cc = s*4 + quad;
        b[nt] = *(const h8*)(Als + n*256 + ((cc ^ (n&7))*8));
      }
      #pragma unroll
      for (int mt=0;mt<2;mt++)
        #pragma unroll
        for (int nt=0;nt<4;nt++)
          acc[mt][nt] = MFMA16H(a[mt], b[nt], acc[mt][nt]);
    }
    __syncthreads();   // all waves done reading Als; T1 aliases it
    // T1 write (register-dependent only)
    #pragma unroll
    for (int mt=0;mt<2;mt++){
      int f0 = (wv*2+mt)*16 + quad*4;
      float4 bb = *(const float4*)(b1 + f0);
      int cg = f0 >> 3, off = (quad&1)*4;
      #pragma unroll
      for (int nt=0;nt<4;nt++){
        int n = nt*16 + l15;
        float v0 = fmaxf(acc[mt][nt][0]+bb.x,0.f), v1 = fmaxf(acc[mt][nt][1]+bb.y,0.f);
        float v2 = fmaxf(acc[mt][nt][2]+bb.z,0.f), v3 = fmaxf(acc[mt][nt][3]+bb.w,0.f);
        uint2 v; v.x = pkrtz(v0,v1); v.y = pkrtz(v2,v3);
        *(uint2*)(T1 + n*256 + ((cg ^ (n&7))*8) + off) = v;
      }
    }
    __syncthreads();
    // ---- GEMM2 ----
    f32x4 acc2[2][4];
    #pragma unroll
    for (int mt=0;mt<2;mt++) for (int nt=0;nt<4;nt++) acc2[mt][nt] = (f32x4)0.f;
    #pragma unroll
    for (int s=0; s<8; s++){
      h8 a[2], b[4];
      #pragma unroll
      for (int mt=0;mt<2;mt++)
        a[mt] = *(const h8*)(W2t + (size_t)((wv*2+mt)*16 + l15)*256 + s*32 + quad*8);
      #pragma unroll
      for (int nt=0;nt<4;nt++){
        int n = nt*16 + l15; int cc = s*4 + quad;
        b[nt] = *(const h8*)(T1 + n*256 + ((cc ^ (n&7))*8));
      }
      #pragma unroll
      for (int mt=0;mt<2;mt++)
        #pragma unroll
        for (int nt=0;nt<4;nt++)
          acc2[mt][nt] = MFMA16H(a[mt], b[nt], acc2[mt][nt]);
    }
    // ---- residual update into xls (packed f16 RMW; relu for c<3) ----
    #pragma unroll
    for (int mt=0;mt<2;mt++){
      int f0 = (wv*2+mt)*16 + quad*4;
      float4 bb = *(const float4*)(b2 + f0);
      int g2 = f0 >> 3, half = (quad&1)*4;
      #pragma unroll
      for (int nt=0;nt<4;nt++){
        int n = nt*16 + l15;
        short* px = xls + n*256 + xg2(g2, n)*8 + half;
        uint2 old = *(uint2*)px;
        u32 n0 = pkrtz(acc2[mt][nt][0]+bb.x, acc2[mt][nt][1]+bb.y);
        u32 n1 = pkrtz(acc2[mt][nt][2]+bb.z, acc2[mt][nt][3]+bb.w);
        if (c < 3){ n0 = pk_relu(n0); n1 = pk_relu(n1); }
        uint2 v; v.x = pk_add(old.x, n0); v.y = pk_add(old.y, n1);
        *(uint2*)px = v;
      }
    }
    __syncthreads();
  }
  // ---- writeout xF (f16, row-major): pure copy ----
  if (nbase + jl < N){
    #pragma unroll
    for (int q=0;q<4;q++){
      uint4 v = *(const uint4*)(xls + jl*256 + xg2(ch4*4+q, jl)*8);
      *(uint4*)(xF + (size_t)(nbase+jl)*256 + ch4*32 + q*8) = v;
    }
  }
}

// ---------- fused head, 512 threads: L1(2 K-halves) -> T -> L2 -> L3 -> loss ----------
// Round-11 config (proven): 32 KB Bls time-multiplexed; (512,4) natural regs.
__global__ __launch_bounds__(512,4) void k_head(
    const short* __restrict__ xF, const short* __restrict__ attrS,
    const int* __restrict__ ei,
    const short* __restrict__ W1t, const float* __restrict__ ob1,
    const short* __restrict__ W2t, const float* __restrict__ ob2,
    const float* __restrict__ W3, const float* __restrict__ ob3,
    const float* __restrict__ dnoise, const int* __restrict__ n2g,
    float* __restrict__ out, int E, int G)
{
  __shared__ uint4 BlsV[8*256];    // 32 KB, time-multiplexed; T aliases after L1
  __shared__ float SedgeW[8][64];  // 2 KB per-wave partials (non-atomic)
  __shared__ float part[4];
  short* Bls = (short*)BlsV;
  short* T   = (short*)BlsV;
  int tid = threadIdx.x;
  int base = blockIdx.x*64;
  int wv = tid>>6, lane = tid&63, quad = lane>>4, l15 = lane&15;
  if (tid < 4) part[tid] = 0.f;
  int g8 = tid & 255, sh = tid >> 8, w4 = g8 >> 6;
  // ---- phase 1a: DMA attr K-slices 8..15 into Bls slots 0..7 ----
  {
    int p = g8>>3, hi = (g8>>2)&1, cs = g8&3;
    int n = p*2 + hi, cc = cs ^ (p&3);
    const short* srcb = attrS + (size_t)(base+n)*256 + cc*8;
    #pragma unroll
    for (int i=0;i<4;i++){
      int s = 8 + i*2 + sh;
      gload_lds16(srcb + (s-8)*32, (char*)BlsV + (size_t)(s-8)*4096 + w4*1024);
    }
  }
  // ---- phase 1b: xr*xc products into registers (overlaps DMA latency) ----
  uint4 pr[4];
  {
    int p = g8>>3, hi = (g8>>2)&1, cs = g8&3;
    int n = p*2 + hi, cc = cs ^ (p&3);
    int rr = ei[base+n], rc = ei[E+base+n];
    const short* xr = xF + (size_t)rr*256 + cc*8;
    const short* xc = xF + (size_t)rc*256 + cc*8;
    #pragma unroll
    for (int i=0;i<4;i++){
      int s = sh*4 + i;
      uint4 va = *(const uint4*)(xr + s*32);
      uint4 vb = *(const uint4*)(xc + s*32);
      pr[i].x = pk_mul(va.x, vb.x); pr[i].y = pk_mul(va.y, vb.y);
      pr[i].z = pk_mul(va.z, vb.z); pr[i].w = pk_mul(va.w, vb.w);
    }
  }
  __syncthreads();   // drains DMA (vmcnt) + all threads ready
  // ---- phase 2: L1 over attr K-half (s=8..15, Bls slot s-8) ----
  f32x4 acc[2][4];
  #pragma unroll
  for (int mt=0;mt<2;mt++) for (int nt=0;nt<4;nt++) acc[mt][nt] = (f32x4)0.f;
  #pragma unroll
  for (int s=8; s<16; s++){
    h8 a[2], b[4];
    #pragma unroll
    for (int mt=0;mt<2;mt++)
      a[mt] = *(const h8*)(W1t + (size_t)((wv*2+mt)*16 + l15)*512 + s*32 + quad*8);
    #pragma unroll
    for (int nt=0;nt<4;nt++)
      b[nt] = *(const h8*)(Bls + (size_t)(s-8)*2048 + frag_off(nt*16 + l15, quad));
    #pragma unroll
    for (int mt=0;mt<2;mt++)
      #pragma unroll
      for (int nt=0;nt<4;nt++)
        acc[mt][nt] = MFMA16H(a[mt], b[nt], acc[mt][nt]);
  }
  __syncthreads();   // all waves done reading attr half
  // ---- phase 3a: dump held xr*xc registers into Bls slots 0..7 ----
  #pragma unroll
  for (int i=0;i<4;i++){
    int s = sh*4 + i;
    *(uint4*)(Bls + (size_t)s*2048 + g8*8) = pr[i];
  }
  __syncthreads();
  // ---- phase 3b: L1 over xr*xc K-half (s=0..7) ----
  #pragma unroll
  for (int s=0; s<8; s++){
    h8 a[2], b[4];
    #pragma unroll
    for (int mt=0;mt<2;mt++)
      a[mt] = *(const h8*)(W1t + (size_t)((wv*2+mt)*16 + l15)*512 + s*32 + quad*8);
    #pragma unroll
    for (int nt=0;nt<4;nt++)
      b[nt] = *(const h8*)(Bls + (size_t)s*2048 + frag_off(nt*16 + l15, quad));
    #pragma unroll
    for (int mt=0;mt<2;mt++)
      #pragma unroll
      for (int nt=0;nt<4;nt++)
        acc[mt][nt] = MFMA16H(a[mt], b[nt], acc[mt][nt]);
  }
  __syncthreads();   // all waves done reading Bls; T aliases it
  #pragma unroll
  for (int mt=0;mt<2;mt++){
    int f0 = (wv*2+mt)*16 + quad*4;
    float4 bb = *(const float4*)(ob1 + f0);
    int c = f0 >> 3, off = (quad&1)*4;
    #pragma unroll
    for (int nt=0;nt<4;nt++){
      int n = nt*16 + l15;
      float v0 = fmaxf(acc[mt][nt][0]+bb.x,0.f), v1 = fmaxf(acc[mt][nt][1]+bb.y,0.f);
      float v2 = fmaxf(acc[mt][nt][2]+bb.z,0.f), v3 = fmaxf(acc[mt][nt][3]+bb.w,0.f);
      uint2 v; v.x = pkrtz(v0,v1); v.y = pkrtz(v2,v3);
      *(uint2*)(T + n*256 + ((c ^ (n&7))*8) + off) = v;
    }
  }
  __syncthreads();
  // ---- L2: 8 barrier-free K-slices; M=128 (8 waves x 16 feats), N=64; A direct ----
  f32x4 acc2[4];
  #pragma unroll
  for (int nt=0;nt<4;nt++) acc2[nt] = (f32x4)0.f;
  #pragma unroll
  for (int s=0; s<8; s++){
    h8 a = *(const h8*)(W2t + (size_t)(wv*16 + l15)*256 + s*32 + quad*8);
    #pragma unroll
    for (int nt=0;nt<4;nt++){
      int n = nt*16 + l15; int cc = s*4 + quad;
      h8 b = *(const h8*)(T + n*256 + ((cc ^ (n&7))*8));
      acc2[nt] = MFMA16H(a, b, acc2[nt]);
    }
  }
  // ---- L3 dot + per-wave partials (non-atomic) ----
  {
    int f0 = wv*16 + quad*4;
    float4 bb = *(const float4*)(ob2 + f0);
    float4 w3 = *(const float4*)(W3 + f0);
    #pragma unroll
    for (int nt=0;nt<4;nt++){
      float p = fmaxf(acc2[nt][0]+bb.x,0.f)*w3.x + fmaxf(acc2[nt][1]+bb.y,0.f)*w3.y
              + fmaxf(acc2[nt][2]+bb.z,0.f)*w3.z + fmaxf(acc2[nt][3]+bb.w,0.f)*w3.w;
      p += __shfl_xor(p, 16);
      p += __shfl_xor(p, 32);
      if (lane < 16) SedgeW[wv][nt*16 + l15] = p;
    }
  }
  __syncthreads();
  // ---- loss + per-block graph reduction (block spans <=2 graphs) ----
  int gbase = n2g[ei[base]];
  if (tid < 64){
    int e = base + tid;
    float sv = ob3[0] + dnoise[e];
    #pragma unroll
    for (int w=0; w<8; w++) sv += SedgeW[w][tid];
    float l = 0.5f*sv*sv;
    int g = n2g[ei[e]] - gbase;     // in {0,1}
    atomicAdd(&part[g & 3], l);
  }
  __syncthreads();
  if (tid < 2 && (gbase + tid) < G)
    atomicAdd(&out[gbase + tid], part[tid]);
}

// =========================== host ===========================
static inline size_t alignup(size_t v){ return (v + 255) & ~(size_t)255; }

extern "C" void kernel_launch(void* const* d_in, const int* in_sizes, int n_in,
                              void* d_out, int out_size, void* d_ws, size_t ws_size,
                              hipStream_t stream) {
  const int*   at    = (const int*)  d_in[0];
  const int*   ei    = (const int*)  d_in[1];
  const int*   etype = (const int*)  d_in[2];
  const int*   n2g   = (const int*)  d_in[3];
  const int*   nl    = (const int*)  d_in[4];
  const float* pos   = (const float*)d_in[5];
  const float* dnoi  = (const float*)d_in[6];
  const float* sig   = (const float*)d_in[7];
  const float* nemb  = (const float*)d_in[8];
  const float* eemb  = (const float*)d_in[9];
  const float* inW1  = (const float*)d_in[10];
  const float* inb1  = (const float*)d_in[11];
  const float* inW2  = (const float*)d_in[12];
  const float* inb2  = (const float*)d_in[13];
  const float* gW1   = (const float*)d_in[14];
  const float* gb1   = (const float*)d_in[15];
  const float* gW2   = (const float*)d_in[16];
  const float* gb2   = (const float*)d_in[17];
  const float* oW1   = (const float*)d_in[18];
  const float* ob1   = (const float*)d_in[19];
  const float* oW2   = (const float*)d_in[20];
  const float* ob2   = (const float*)d_in[21];
  const float* oW3   = (const float*)d_in[22];
  const float* ob3   = (const float*)d_in[23];
  float* out = (float*)d_out;

  const int N = in_sizes[0];
  const int E = in_sizes[2];
  const int G = in_sizes[4];
  const int H = 256;

  char* w = (char*)d_ws;
  size_t off = 0;
  size_t o_attr  = off; off = alignup(off + (size_t)(E+1)*H*2);  // +1 zero row
  size_t o_xF    = off; off = alignup(off + (size_t)N*H*2);
  size_t o_pd    = off; off = alignup(off + (size_t)E*4);
  size_t o_cnt   = off; off = alignup(off + (size_t)N*4);
  size_t o_inl   = off; off = alignup(off + (size_t)N*8*4);
  size_t o_w2t   = off; off = alignup(off + (size_t)H*H*2);
  size_t o_gw1t  = off; off = alignup(off + (size_t)4*H*H*2);
  size_t o_gw2t  = off; off = alignup(off + (size_t)4*H*H*2);
  size_t o_ow1t  = off; off = alignup(off + (size_t)H*2*H*2);
  size_t o_ow2t  = off; off = alignup(off + (size_t)(H/2)*H*2);
  (void)ws_size; (void)n_in; (void)out_size;

  short* attrS = (short*)(w + o_attr);
  short* xF    = (short*)(w + o_xF);
  float* pd    = (float*)(w + o_pd);
  int*   cnt   = (int*)  (w + o_cnt);
  int*   inl   = (int*)  (w + o_inl);
  short* w2t   = (short*)(w + o_w2t);
  short* gw1t  = (short*)(w + o_gw1t);
  short* gw2t  = (short*)(w + o_gw2t);
  short* ow1t  = (short*)(w + o_ow1t);
  short* ow2t  = (short*)(w + o_ow2t);

  hipMemsetAsync(cnt, 0, (size_t)N*4, stream);

  // merged: weight-convert + edge-pre + zero(out) + zero(attr pad row)
  k_init<<<1090, 256, 0, stream>>>(inW2, gW1, gW2, oW1, oW2,
                                   w2t, gw1t, gw2t, ow1t, ow2t,
                                   ei, n2g, nl, sig, pos, dnoi, E,
                                   pd, cnt, inl,
                                   out, G, attrS + (size_t)E*H);

  k_attr<<<E/64, 256, 0, stream>>>(pd, inW1, inb1, w2t, inb2, etype, eemb, attrS, E);

  k_conv4<<<(G+1)/2, 512, 0, stream>>>(at, nemb, attrS, ei, cnt, inl,
                                       gw1t, gb1, gw2t, gb2, xF, E, N);

  k_head<<<E/64, 512, 0, stream>>>(xF, attrS, ei, ow1t, ob1, ow2t, ob2,
                                   oW3, ob3, dnoi, n2g, out, E, G);
}

// Round 15
// 484.591 us; speedup vs baseline: 1.1312x; 1.1312x over previous
//
#include <hip/hip_runtime.h>
#include <math.h>

typedef unsigned int u32;
typedef __attribute__((ext_vector_type(2))) _Float16 h2;
typedef __attribute__((ext_vector_type(8))) _Float16 h8;
typedef __attribute__((ext_vector_type(4))) float f32x4;

#define MFMA16H(a,b,c) __builtin_amdgcn_mfma_f32_16x16x32_f16(a,b,c,0,0,0)

// ---------- f16 packed helpers ----------
__device__ __forceinline__ u32 pkrtz(float a, float b){
  auto r = __builtin_amdgcn_cvt_pkrtz(a, b);   // __fp16 ext_vector(2)
  return *(u32*)&r;
}
__device__ __forceinline__ uint4 pack8h(const float* f){
  uint4 v; v.x = pkrtz(f[0],f[1]); v.y = pkrtz(f[2],f[3]);
  v.z = pkrtz(f[4],f[5]); v.w = pkrtz(f[6],f[7]); return v;
}
__device__ __forceinline__ u32 pk_add(u32 a, u32 b){
  h2 r = *(h2*)&a + *(h2*)&b; return *(u32*)&r;
}
__device__ __forceinline__ u32 pk_mul(u32 a, u32 b){
  h2 r = *(h2*)&a * *(h2*)&b; return *(u32*)&r;
}
__device__ __forceinline__ u32 pk_relu(u32 a){
  h2 z = {(_Float16)0.f, (_Float16)0.f};
  h2 r = __builtin_elementwise_max(*(h2*)&a, z);
  return *(u32*)&r;
}

// async global->LDS, 16B/lane; dest = wave-uniform base + lane*16 (src per-lane OK)
__device__ __forceinline__ void gload_lds16(const void* g, void* l){
  __builtin_amdgcn_global_load_lds((const __attribute__((address_space(1))) unsigned int*)g,
                                   (__attribute__((address_space(3))) unsigned int*)l,
                                   16, 0, 0);
}

// LDS fragment offset (shorts) in paired-macro-row granule layout
__device__ __forceinline__ int frag_off(int f, int quad){
  return (f>>1)*64 + (f&1)*32 + ((quad ^ ((f>>1)&3))*8);
}

// f16-row granule swizzle: row = 32 granules x 8 halfs; mixes ch (=g>>1) and row into banks
__device__ __forceinline__ int xg2(int g, int r){ return g ^ ((r ^ (g>>1)) & 7); }

// ---------- merged init kernel: weight-convert + per-edge pre + small zeroing ----------
__global__ void k_init(const float* __restrict__ inW2, const float* __restrict__ gW1,
                       const float* __restrict__ gW2, const float* __restrict__ oW1,
                       const float* __restrict__ oW2,
                       short* __restrict__ w2t, short* __restrict__ gw1t,
                       short* __restrict__ gw2t, short* __restrict__ ow1t,
                       short* __restrict__ ow2t,
                       const int* __restrict__ ei, const int* __restrict__ n2g,
                       const int* __restrict__ nl, const float* __restrict__ sigmas,
                       const float* __restrict__ pos, const float* __restrict__ dn, int E,
                       float* __restrict__ pd, int* __restrict__ cnt, int* __restrict__ inlist,
                       float* __restrict__ out, int G, short* __restrict__ attrPad){
  int blk = blockIdx.x;
  int tid = threadIdx.x;
  if (blk < 368){
    int gidx = blk*256 + tid;
    const float* src; short* dst; int t, K8, Nf;
    if (gidx < 8192)      { src = inW2; dst = w2t; t = gidx; K8 = 32; Nf = 256; }
    else if (gidx < 40960){ int r = gidx-8192;  int c = r>>13; t = r&8191;
                            src = gW1 + (size_t)c*65536; dst = gw1t + (size_t)c*65536; K8 = 32; Nf = 256; }
    else if (gidx < 73728){ int r = gidx-40960; int c = r>>13; t = r&8191;
                            src = gW2 + (size_t)c*65536; dst = gw2t + (size_t)c*65536; K8 = 32; Nf = 256; }
    else if (gidx < 90112){ t = gidx-73728; src = oW1; dst = ow1t; K8 = 64; Nf = 256; }
    else if (gidx < 94208){ t = gidx-90112; src = oW2; dst = ow2t; K8 = 32; Nf = 128; }
    else return;
    int f = t / K8, c = t - f*K8;
    float v[8];
    #pragma unroll
    for (int j=0;j<8;j++) v[j] = src[(size_t)(c*8+j)*Nf + f];
    ((uint4*)dst)[t] = pack8h(v);
  } else if (blk < 1088){
    int e = (blk-368)*256 + tid;
    if (e >= E) return;
    int r = ei[e], c = ei[E+e];
    float sg = sigmas[nl[n2g[r]]];
    float dx = pos[3*r]-pos[3*c], dy = pos[3*r+1]-pos[3*c+1], dz = pos[3*r+2]-pos[3*c+2];
    float d = sqrtf(dx*dx + dy*dy + dz*dz);
    pd[e] = d + dn[e]*sg;
    int slot = atomicAdd(&cnt[c], 1);
    if (slot < 8) inlist[c*8 + slot] = e;
  } else if (blk == 1088){
    for (int i = tid; i < G; i += 256) out[i] = 0.f;
  } else {
    if (tid < 128) ((u32*)attrPad)[tid] = 0u;
  }
}

// ---------- edge_attr: barrier-free, no LDS. B computed in registers ----------
__global__ __launch_bounds__(256) void k_attr(
    const float* __restrict__ pd, const float* __restrict__ W1, const float* __restrict__ b1,
    const short* __restrict__ W2t, const float* __restrict__ b2,
    const int* __restrict__ etype, const float* __restrict__ eemb,
    short* __restrict__ attr, int E)
{
  int tid = threadIdx.x;
  int base = blockIdx.x*64;
  int wv = tid>>6, lane = tid&63, quad = lane>>4, l15 = lane&15;
  float pdv[4];
  #pragma unroll
  for (int nt=0;nt<4;nt++) pdv[nt] = pd[base + nt*16 + l15];
  f32x4 acc[4][4];
  #pragma unroll
  for (int mt=0;mt<4;mt++) for (int nt=0;nt<4;nt++) acc[mt][nt] = (f32x4)0.f;
  #pragma unroll
  for (int s=0; s<8; s++){
    int k0 = s*32 + quad*8;
    float4 w1a = *(const float4*)(W1 + k0), w1b = *(const float4*)(W1 + k0 + 4);
    float4 b1a = *(const float4*)(b1 + k0), b1b = *(const float4*)(b1 + k0 + 4);
    h8 a[4], b[4];
    #pragma unroll
    for (int mt=0;mt<4;mt++){
      int f = (wv*4+mt)*16 + l15;
      a[mt] = *(const h8*)(W2t + (size_t)f*256 + k0);
    }
    #pragma unroll
    for (int nt=0;nt<4;nt++){
      float p = pdv[nt];
      float f[8] = {fmaxf(p*w1a.x+b1a.x,0.f), fmaxf(p*w1a.y+b1a.y,0.f),
                    fmaxf(p*w1a.z+b1a.z,0.f), fmaxf(p*w1a.w+b1a.w,0.f),
                    fmaxf(p*w1b.x+b1b.x,0.f), fmaxf(p*w1b.y+b1b.y,0.f),
                    fmaxf(p*w1b.z+b1b.z,0.f), fmaxf(p*w1b.w+b1b.w,0.f)};
      uint4 u = pack8h(f);
      b[nt] = *(h8*)&u;
    }
    #pragma unroll
    for (int mt=0;mt<4;mt++)
      #pragma unroll
      for (int nt=0;nt<4;nt++)
        acc[mt][nt] = MFMA16H(a[mt], b[nt], acc[mt][nt]);
  }
  #pragma unroll
  for (int nt=0;nt<4;nt++){
    int e = base + nt*16 + l15;
    int et = etype[e];
    #pragma unroll
    for (int mt=0;mt<4;mt++){
      int f0 = (wv*4+mt)*16 + quad*4;
      float4 bb = *(const float4*)(b2 + f0);
      float4 em = *(const float4*)(eemb + (size_t)et*256 + f0);
      float v0 = (acc[mt][nt][0]+bb.x)*em.x, v1 = (acc[mt][nt][1]+bb.y)*em.y;
      float v2 = (acc[mt][nt][2]+bb.z)*em.z, v3 = (acc[mt][nt][3]+bb.w)*em.w;
      uint2 v; v.x = pkrtz(v0,v1); v.y = pkrtz(v2,v3);
      *(uint2*)(attr + (size_t)e*256 + f0) = v;
    }
  }
}

// ---------- fused 4-conv kernel: 2 GRAPHS (64 nodes) per block, 512 threads ----------
// Round-15: REVERT to the round-13 best-measured config (485.9 us total).
// Proven equilibrium: two sequential 16-feat passes (unroll 1 prevents the
// r7/r8 pass-merge spill), 32B-granule attr reads (traffic minimum; r14's
// 16B 4-pass cost +53% FETCH), 2 blocks/CU, no spill (WRITE 16.4 MB).
__global__ __launch_bounds__(512,4) void k_conv4(
    const int* __restrict__ at, const float* __restrict__ nemb,
    const short* __restrict__ attrS, const int* __restrict__ ei,
    const int* __restrict__ cnt, const int* __restrict__ inlist,
    const short* __restrict__ gw1t, const float* __restrict__ gb1,
    const short* __restrict__ gw2t, const float* __restrict__ gb2,
    short* __restrict__ xF, int E, int N)
{
  __shared__ short xls[65*256];       // 32.5 KB f16 state (64 nodes); row 64 = zero
  __shared__ uint4 AlsV[64*32];       // 32 KB; Als aliases T1
  short* Als = (short*)AlsV;
  short* T1  = (short*)AlsV;
  int tid = threadIdx.x;
  int nbase = blockIdx.x*64;
  int wv = tid>>6, lane = tid&63, quad = lane>>4, l15 = lane&15;
  int jl = tid>>3, ch4 = tid&7;       // 8 threads/node, 32 feats each

  // ---- topology: unconditional loads + selects, packed e|r<<20 (r<=64: 7b) ----
  int topo[8];
  {
    int j = nbase + jl;
    int jj = (j < N) ? j : 0;
    int deg = (j < N) ? min(cnt[jj], 8) : 0;
    int4 L0 = *(const int4*)(inlist + jj*8);
    int4 L1 = *(const int4*)(inlist + jj*8 + 4);
    int raw[8] = {L0.x,L0.y,L0.z,L0.w,L1.x,L1.y,L1.z,L1.w};
    #pragma unroll
    for (int s=0;s<8;s++){
      int e = (s < deg) ? raw[s] : E;            // E = zeroed attr row
      int r = ei[e] - nbase;                     // ei[E] in-bounds (2E array)
      if (s >= deg) r = 64;                      // 64 = zeroed x row
      topo[s] = e | (r << 20);
    }
  }
  // ---- init xls (f16) from node_emb[at]; zero row 64 ----
  {
    int j = nbase + jl;
    int a = (j < N) ? at[j] : 0;
    const float* src = nemb + (size_t)a*256 + ch4*32;
    #pragma unroll
    for (int q=0;q<4;q++){
      float f[8];
      float4 v0 = *(const float4*)(src + q*8);
      float4 v1 = *(const float4*)(src + q*8 + 4);
      f[0]=v0.x; f[1]=v0.y; f[2]=v0.z; f[3]=v0.w;
      f[4]=v1.x; f[5]=v1.y; f[6]=v1.z; f[7]=v1.w;
      *(uint4*)(xls + jl*256 + xg2(ch4*4+q, jl)*8) = pack8h(f);
    }
    if (tid < 32){ uint4 z; z.x=z.y=z.z=z.w=0u; ((uint4*)(xls + 64*256))[tid] = z; }
  }
  __syncthreads();
  for (int c=0; c<4; c++){
    const short* W1t = gw1t + (size_t)c*65536;
    const short* W2t = gw2t + (size_t)c*65536;
    const float* b1 = gb1 + c*256;
    const float* b2 = gb2 + c*256;
    // ---- gather into Als: TWO sequential 16-feat passes; bounded load batch ----
    #pragma unroll 1
    for (int q=0; q<2; q++){
      int c0 = ch4*4 + q*2, c1 = c0 + 1;
      uint4 A0 = *(const uint4*)(xls + jl*256 + xg2(c0, jl)*8);
      uint4 A1 = *(const uint4*)(xls + jl*256 + xg2(c1, jl)*8);
      #pragma unroll 4
      for (int s=0; s<8; s++){
        int e = topo[s] & 0xFFFFF;
        int r = topo[s] >> 20;
        const short* ar = attrS + (size_t)e*256 + ch4*32 + q*16;
        uint4 x0 = *(const uint4*)(xls + r*256 + xg2(c0, r)*8);
        uint4 x1 = *(const uint4*)(xls + r*256 + xg2(c1, r)*8);
        uint4 a0 = *(const uint4*)(ar);
        uint4 a1 = *(const uint4*)(ar + 8);
        A0.x = pk_add(A0.x, pk_relu(pk_add(x0.x, a0.x)));
        A0.y = pk_add(A0.y, pk_relu(pk_add(x0.y, a0.y)));
        A0.z = pk_add(A0.z, pk_relu(pk_add(x0.z, a0.z)));
        A0.w = pk_add(A0.w, pk_relu(pk_add(x0.w, a0.w)));
        A1.x = pk_add(A1.x, pk_relu(pk_add(x1.x, a1.x)));
        A1.y = pk_add(A1.y, pk_relu(pk_add(x1.y, a1.y)));
        A1.z = pk_add(A1.z, pk_relu(pk_add(x1.z, a1.z)));
        A1.w = pk_add(A1.w, pk_relu(pk_add(x1.w, a1.w)));
      }
      *(uint4*)(Als + jl*256 + ((c0 ^ (jl&7))*8)) = A0;
      *(uint4*)(Als + jl*256 + ((c1 ^ (jl&7))*8)) = A1;
    }
    __syncthreads();
    // ---- GEMM1: M=256 (8 waves x 32 feats), N=64, K=256; A direct from L2 ----
    f32x4 acc[2][4];
    #pragma unroll
    for (int mt=0;mt<2;mt++) for (int nt=0;nt<4;nt++) acc[mt][nt] = (f32x4)0.f;
    #pragma unroll
    for (int s=0; s<8; s++){
      h8 a[2], b[4];
      #pragma unroll
      for (int mt=0;mt<2;mt++)
        a[mt] = *(const h8*)(W1t + (size_t)((wv*2+mt)*16 + l15)*256 + s*32 + quad*8);
      #pragma unroll
      for (int nt=0;nt<4;nt++){
        int n = nt*16 + l15; int cc = s*4 + quad;
        b[nt] = *(const h8*)(Als + n*256 + ((cc ^ (n&7))*8));
      }
      #pragma unroll
      for (int mt=0;mt<2;mt++)
        #pragma unroll
        for (int nt=0;nt<4;nt++)
          acc[mt][nt] = MFMA16H(a[mt], b[nt], acc[mt][nt]);
    }
    __syncthreads();   // all waves done reading Als; T1 aliases it
    // T1 write (register-dependent only)
    #pragma unroll
    for (int mt=0;mt<2;mt++){
      int f0 = (wv*2+mt)*16 + quad*4;
      float4 bb = *(const float4*)(b1 + f0);
      int cg = f0 >> 3, off = (quad&1)*4;
      #pragma unroll
      for (int nt=0;nt<4;nt++){
        int n = nt*16 + l15;
        float v0 = fmaxf(acc[mt][nt][0]+bb.x,0.f), v1 = fmaxf(acc[mt][nt][1]+bb.y,0.f);
        float v2 = fmaxf(acc[mt][nt][2]+bb.z,0.f), v3 = fmaxf(acc[mt][nt][3]+bb.w,0.f);
        uint2 v; v.x = pkrtz(v0,v1); v.y = pkrtz(v2,v3);
        *(uint2*)(T1 + n*256 + ((cg ^ (n&7))*8) + off) = v;
      }
    }
    __syncthreads();
    // ---- GEMM2 ----
    f32x4 acc2[2][4];
    #pragma unroll
    for (int mt=0;mt<2;mt++) for (int nt=0;nt<4;nt++) acc2[mt][nt] = (f32x4)0.f;
    #pragma unroll
    for (int s=0; s<8; s++){
      h8 a[2], b[4];
      #pragma unroll
      for (int mt=0;mt<2;mt++)
        a[mt] = *(const h8*)(W2t + (size_t)((wv*2+mt)*16 + l15)*256 + s*32 + quad*8);
      #pragma unroll
      for (int nt=0;nt<4;nt++){
        int n = nt*16 + l15; int cc = s*4 + quad;
        b[nt] = *(const h8*)(T1 + n*256 + ((cc ^ (n&7))*8));
      }
      #pragma unroll
      for (int mt=0;mt<2;mt++)
        #pragma unroll
        for (int nt=0;nt<4;nt++)
          acc2[mt][nt] = MFMA16H(a[mt], b[nt], acc2[mt][nt]);
    }
    // ---- residual update into xls (packed f16 RMW; relu for c<3) ----
    #pragma unroll
    for (int mt=0;mt<2;mt++){
      int f0 = (wv*2+mt)*16 + quad*4;
      float4 bb = *(const float4*)(b2 + f0);
      int g2 = f0 >> 3, half = (quad&1)*4;
      #pragma unroll
      for (int nt=0;nt<4;nt++){
        int n = nt*16 + l15;
        short* px = xls + n*256 + xg2(g2, n)*8 + half;
        uint2 old = *(uint2*)px;
        u32 n0 = pkrtz(acc2[mt][nt][0]+bb.x, acc2[mt][nt][1]+bb.y);
        u32 n1 = pkrtz(acc2[mt][nt][2]+bb.z, acc2[mt][nt][3]+bb.w);
        if (c < 3){ n0 = pk_relu(n0); n1 = pk_relu(n1); }
        uint2 v; v.x = pk_add(old.x, n0); v.y = pk_add(old.y, n1);
        *(uint2*)px = v;
      }
    }
    __syncthreads();
  }
  // ---- writeout xF (f16, row-major): pure copy ----
  if (nbase + jl < N){
    #pragma unroll
    for (int q=0;q<4;q++){
      uint4 v = *(const uint4*)(xls + jl*256 + xg2(ch4*4+q, jl)*8);
      *(uint4*)(xF + (size_t)(nbase+jl)*256 + ch4*32 + q*8) = v;
    }
  }
}

// ---------- fused head, 512 threads: L1(2 K-halves) -> T -> L2 -> L3 -> loss ----------
// Round-11 config (proven): 32 KB Bls time-multiplexed; (512,4) natural regs.
__global__ __launch_bounds__(512,4) void k_head(
    const short* __restrict__ xF, const short* __restrict__ attrS,
    const int* __restrict__ ei,
    const short* __restrict__ W1t, const float* __restrict__ ob1,
    const short* __restrict__ W2t, const float* __restrict__ ob2,
    const float* __restrict__ W3, const float* __restrict__ ob3,
    const float* __restrict__ dnoise, const int* __restrict__ n2g,
    float* __restrict__ out, int E, int G)
{
  __shared__ uint4 BlsV[8*256];    // 32 KB, time-multiplexed; T aliases after L1
  __shared__ float SedgeW[8][64];  // 2 KB per-wave partials (non-atomic)
  __shared__ float part[4];
  short* Bls = (short*)BlsV;
  short* T   = (short*)BlsV;
  int tid = threadIdx.x;
  int base = blockIdx.x*64;
  int wv = tid>>6, lane = tid&63, quad = lane>>4, l15 = lane&15;
  if (tid < 4) part[tid] = 0.f;
  int g8 = tid & 255, sh = tid >> 8, w4 = g8 >> 6;
  // ---- phase 1a: DMA attr K-slices 8..15 into Bls slots 0..7 ----
  {
    int p = g8>>3, hi = (g8>>2)&1, cs = g8&3;
    int n = p*2 + hi, cc = cs ^ (p&3);
    const short* srcb = attrS + (size_t)(base+n)*256 + cc*8;
    #pragma unroll
    for (int i=0;i<4;i++){
      int s = 8 + i*2 + sh;
      gload_lds16(srcb + (s-8)*32, (char*)BlsV + (size_t)(s-8)*4096 + w4*1024);
    }
  }
  // ---- phase 1b: xr*xc products into registers (overlaps DMA latency) ----
  uint4 pr[4];
  {
    int p = g8>>3, hi = (g8>>2)&1, cs = g8&3;
    int n = p*2 + hi, cc = cs ^ (p&3);
    int rr = ei[base+n], rc = ei[E+base+n];
    const short* xr = xF + (size_t)rr*256 + cc*8;
    const short* xc = xF + (size_t)rc*256 + cc*8;
    #pragma unroll
    for (int i=0;i<4;i++){
      int s = sh*4 + i;
      uint4 va = *(const uint4*)(xr + s*32);
      uint4 vb = *(const uint4*)(xc + s*32);
      pr[i].x = pk_mul(va.x, vb.x); pr[i].y = pk_mul(va.y, vb.y);
      pr[i].z = pk_mul(va.z, vb.z); pr[i].w = pk_mul(va.w, vb.w);
    }
  }
  __syncthreads();   // drains DMA (vmcnt) + all threads ready
  // ---- phase 2: L1 over attr K-half (s=8..15, Bls slot s-8) ----
  f32x4 acc[2][4];
  #pragma unroll
  for (int mt=0;mt<2;mt++) for (int nt=0;nt<4;nt++) acc[mt][nt] = (f32x4)0.f;
  #pragma unroll
  for (int s=8; s<16; s++){
    h8 a[2], b[4];
    #pragma unroll
    for (int mt=0;mt<2;mt++)
      a[mt] = *(const h8*)(W1t + (size_t)((wv*2+mt)*16 + l15)*512 + s*32 + quad*8);
    #pragma unroll
    for (int nt=0;nt<4;nt++)
      b[nt] = *(const h8*)(Bls + (size_t)(s-8)*2048 + frag_off(nt*16 + l15, quad));
    #pragma unroll
    for (int mt=0;mt<2;mt++)
      #pragma unroll
      for (int nt=0;nt<4;nt++)
        acc[mt][nt] = MFMA16H(a[mt], b[nt], acc[mt][nt]);
  }
  __syncthreads();   // all waves done reading attr half
  // ---- phase 3a: dump held xr*xc registers into Bls slots 0..7 ----
  #pragma unroll
  for (int i=0;i<4;i++){
    int s = sh*4 + i;
    *(uint4*)(Bls + (size_t)s*2048 + g8*8) = pr[i];
  }
  __syncthreads();
  // ---- phase 3b: L1 over xr*xc K-half (s=0..7) ----
  #pragma unroll
  for (int s=0; s<8; s++){
    h8 a[2], b[4];
    #pragma unroll
    for (int mt=0;mt<2;mt++)
      a[mt] = *(const h8*)(W1t + (size_t)((wv*2+mt)*16 + l15)*512 + s*32 + quad*8);
    #pragma unroll
    for (int nt=0;nt<4;nt++)
      b[nt] = *(const h8*)(Bls + (size_t)s*2048 + frag_off(nt*16 + l15, quad));
    #pragma unroll
    for (int mt=0;mt<2;mt++)
      #pragma unroll
      for (int nt=0;nt<4;nt++)
        acc[mt][nt] = MFMA16H(a[mt], b[nt], acc[mt][nt]);
  }
  __syncthreads();   // all waves done reading Bls; T aliases it
  #pragma unroll
  for (int mt=0;mt<2;mt++){
    int f0 = (wv*2+mt)*16 + quad*4;
    float4 bb = *(const float4*)(ob1 + f0);
    int c = f0 >> 3, off = (quad&1)*4;
    #pragma unroll
    for (int nt=0;nt<4;nt++){
      int n = nt*16 + l15;
      float v0 = fmaxf(acc[mt][nt][0]+bb.x,0.f), v1 = fmaxf(acc[mt][nt][1]+bb.y,0.f);
      float v2 = fmaxf(acc[mt][nt][2]+bb.z,0.f), v3 = fmaxf(acc[mt][nt][3]+bb.w,0.f);
      uint2 v; v.x = pkrtz(v0,v1); v.y = pkrtz(v2,v3);
      *(uint2*)(T + n*256 + ((c ^ (n&7))*8) + off) = v;
    }
  }
  __syncthreads();
  // ---- L2: 8 barrier-free K-slices; M=128 (8 waves x 16 feats), N=64; A direct ----
  f32x4 acc2[4];
  #pragma unroll
  for (int nt=0;nt<4;nt++) acc2[nt] = (f32x4)0.f;
  #pragma unroll
  for (int s=0; s<8; s++){
    h8 a = *(const h8*)(W2t + (size_t)(wv*16 + l15)*256 + s*32 + quad*8);
    #pragma unroll
    for (int nt=0;nt<4;nt++){
      int n = nt*16 + l15; int cc = s*4 + quad;
      h8 b = *(const h8*)(T + n*256 + ((cc ^ (n&7))*8));
      acc2[nt] = MFMA16H(a, b, acc2[nt]);
    }
  }
  // ---- L3 dot + per-wave partials (non-atomic) ----
  {
    int f0 = wv*16 + quad*4;
    float4 bb = *(const float4*)(ob2 + f0);
    float4 w3 = *(const float4*)(W3 + f0);
    #pragma unroll
    for (int nt=0;nt<4;nt++){
      float p = fmaxf(acc2[nt][0]+bb.x,0.f)*w3.x + fmaxf(acc2[nt][1]+bb.y,0.f)*w3.y
              + fmaxf(acc2[nt][2]+bb.z,0.f)*w3.z + fmaxf(acc2[nt][3]+bb.w,0.f)*w3.w;
      p += __shfl_xor(p, 16);
      p += __shfl_xor(p, 32);
      if (lane < 16) SedgeW[wv][nt*16 + l15] = p;
    }
  }
  __syncthreads();
  // ---- loss + per-block graph reduction (block spans <=2 graphs) ----
  int gbase = n2g[ei[base]];
  if (tid < 64){
    int e = base + tid;
    float sv = ob3[0] + dnoise[e];
    #pragma unroll
    for (int w=0; w<8; w++) sv += SedgeW[w][tid];
    float l = 0.5f*sv*sv;
    int g = n2g[ei[e]] - gbase;     // in {0,1}
    atomicAdd(&part[g & 3], l);
  }
  __syncthreads();
  if (tid < 2 && (gbase + tid) < G)
    atomicAdd(&out[gbase + tid], part[tid]);
}

// =========================== host ===========================
static inline size_t alignup(size_t v){ return (v + 255) & ~(size_t)255; }

extern "C" void kernel_launch(void* const* d_in, const int* in_sizes, int n_in,
                              void* d_out, int out_size, void* d_ws, size_t ws_size,
                              hipStream_t stream) {
  const int*   at    = (const int*)  d_in[0];
  const int*   ei    = (const int*)  d_in[1];
  const int*   etype = (const int*)  d_in[2];
  const int*   n2g   = (const int*)  d_in[3];
  const int*   nl    = (const int*)  d_in[4];
  const float* pos   = (const float*)d_in[5];
  const float* dnoi  = (const float*)d_in[6];
  const float* sig   = (const float*)d_in[7];
  const float* nemb  = (const float*)d_in[8];
  const float* eemb  = (const float*)d_in[9];
  const float* inW1  = (const float*)d_in[10];
  const float* inb1  = (const float*)d_in[11];
  const float* inW2  = (const float*)d_in[12];
  const float* inb2  = (const float*)d_in[13];
  const float* gW1   = (const float*)d_in[14];
  const float* gb1   = (const float*)d_in[15];
  const float* gW2   = (const float*)d_in[16];
  const float* gb2   = (const float*)d_in[17];
  const float* oW1   = (const float*)d_in[18];
  const float* ob1   = (const float*)d_in[19];
  const float* oW2   = (const float*)d_in[20];
  const float* ob2   = (const float*)d_in[21];
  const float* oW3   = (const float*)d_in[22];
  const float* ob3   = (const float*)d_in[23];
  float* out = (float*)d_out;

  const int N = in_sizes[0];
  const int E = in_sizes[2];
  const int G = in_sizes[4];
  const int H = 256;

  char* w = (char*)d_ws;
  size_t off = 0;
  size_t o_attr  = off; off = alignup(off + (size_t)(E+1)*H*2);  // +1 zero row
  size_t o_xF    = off; off = alignup(off + (size_t)N*H*2);
  size_t o_pd    = off; off = alignup(off + (size_t)E*4);
  size_t o_cnt   = off; off = alignup(off + (size_t)N*4);
  size_t o_inl   = off; off = alignup(off + (size_t)N*8*4);
  size_t o_w2t   = off; off = alignup(off + (size_t)H*H*2);
  size_t o_gw1t  = off; off = alignup(off + (size_t)4*H*H*2);
  size_t o_gw2t  = off; off = alignup(off + (size_t)4*H*H*2);
  size_t o_ow1t  = off; off = alignup(off + (size_t)H*2*H*2);
  size_t o_ow2t  = off; off = alignup(off + (size_t)(H/2)*H*2);
  (void)ws_size; (void)n_in; (void)out_size;

  short* attrS = (short*)(w + o_attr);
  short* xF    = (short*)(w + o_xF);
  float* pd    = (float*)(w + o_pd);
  int*   cnt   = (int*)  (w + o_cnt);
  int*   inl   = (int*)  (w + o_inl);
  short* w2t   = (short*)(w + o_w2t);
  short* gw1t  = (short*)(w + o_gw1t);
  short* gw2t  = (short*)(w + o_gw2t);
  short* ow1t  = (short*)(w + o_ow1t);
  short* ow2t  = (short*)(w + o_ow2t);

  hipMemsetAsync(cnt, 0, (size_t)N*4, stream);

  // merged: weight-convert + edge-pre + zero(out) + zero(attr pad row)
  k_init<<<1090, 256, 0, stream>>>(inW2, gW1, gW2, oW1, oW2,
                                   w2t, gw1t, gw2t, ow1t, ow2t,
                                   ei, n2g, nl, sig, pos, dnoi, E,
                                   pd, cnt, inl,
                                   out, G, attrS + (size_t)E*H);

  k_attr<<<E/64, 256, 0, stream>>>(pd, inW1, inb1, w2t, inb2, etype, eemb, attrS, E);

  k_conv4<<<(G+1)/2, 512, 0, stream>>>(at, nemb, attrS, ei, cnt, inl,
                                       gw1t, gb1, gw2t, gb2, xF, E, N);

  k_head<<<E/64, 512, 0, stream>>>(xF, attrS, ei, ow1t, ob1, ow2t, ob2,
                                   oW3, ob3, dnoi, n2g, out, E, G);
}